// Round 2
// baseline (174.377 us; speedup 1.0000x reference)
//
#include <hip/hip_runtime.h>

#define NB 4
#define NC 128
#define NH 128
#define NW 240
#define NE 64
#define NK 9
#define PLANE (NH*NW)        // 30720: stride between channels
#define CHW (NC*PLANE)

typedef __attribute__((ext_vector_type(8))) short short8;
typedef __attribute__((ext_vector_type(4))) float f32x4;

__device__ __forceinline__ unsigned short f2bf(float f){
  unsigned u = __float_as_uint(f);
  u += 0x7fffu + ((u>>16)&1u);           // RNE
  return (unsigned short)(u>>16);
}
__device__ __forceinline__ float bfl(unsigned v){ return __uint_as_float(v<<16); }
__device__ __forceinline__ float bfh(unsigned v){ return __uint_as_float(v & 0xffff0000u); }

// LDS: stag 240x136 bf16 (x row transposed, +8 pad), phi 64x136 bf16,
// FL/FR 240x64 bf16 XOR-swizzled on 16B chunks. Total 144,128 B -> 1 block/CU.
__global__ __launch_bounds__(256, 1)
void corr_kernel(const float* __restrict__ xL,
                 const float* __restrict__ xR,
                 const float* __restrict__ d0g,
                 const float* __restrict__ phig,
                 float* __restrict__ outg)
{
  __shared__ __attribute__((aligned(16))) unsigned short stag[NW*136];
  __shared__ __attribute__((aligned(16))) unsigned short phis[NE*136];
  __shared__ __attribute__((aligned(16))) unsigned short FLb[NW*64];
  __shared__ __attribute__((aligned(16))) unsigned short FRb[NW*64];

  const int tid  = threadIdx.x;
  const int lane = tid & 63;
  const int wv   = tid >> 6;
  const int b    = blockIdx.x >> 7;
  const int h    = blockIdx.x & 127;
  const size_t base = (size_t)b*CHW + (size_t)h*NW;

  // ---------------- issue global loads for L (+phi), fp32 ----------------
  float4 le0[8], le1[8], lo0[8], lo1[8];
  #pragma unroll
  for (int i = 0; i < 8; ++i) {
    int tau = tid + 256*i;
    if (tau < 1920) {
      int c2 = tau & 63, wo = tau >> 6;
      size_t off = base + (size_t)(2*c2)*PLANE + 8*wo;
      le0[i] = *(const float4*)(xL + off);
      le1[i] = *(const float4*)(xL + off + 4);
      lo0[i] = *(const float4*)(xL + off + PLANE);
      lo1[i] = *(const float4*)(xL + off + PLANE + 4);
    }
  }
  float4 ph[8];                          // phi: 8192 floats = 256*8 float4 exactly
  #pragma unroll
  for (int i = 0; i < 8; ++i) {
    int tau = tid + 256*i;
    int row = tau >> 5, ch = tau & 31;
    ph[i] = *(const float4*)(phig + row*128 + 4*ch);
  }

  // ---------------- LDS writes: phi + L transposed (fp32->bf16) ----------------
  #pragma unroll
  for (int i = 0; i < 8; ++i) {
    int tau = tid + 256*i;
    int row = tau >> 5, ch = tau & 31;
    unsigned w0 = (unsigned)f2bf(ph[i].x) | ((unsigned)f2bf(ph[i].y) << 16);
    unsigned w1 = (unsigned)f2bf(ph[i].z) | ((unsigned)f2bf(ph[i].w) << 16);
    uint2 pk; pk.x = w0; pk.y = w1;
    *(uint2*)&phis[row*136 + 4*ch] = pk;
  }
  #pragma unroll
  for (int i = 0; i < 8; ++i) {
    int tau = tid + 256*i;
    if (tau < 1920) {
      int c2 = tau & 63, wo = tau >> 6;
      float fe[8] = {le0[i].x, le0[i].y, le0[i].z, le0[i].w,
                     le1[i].x, le1[i].y, le1[i].z, le1[i].w};
      float fo[8] = {lo0[i].x, lo0[i].y, lo0[i].z, lo0[i].w,
                     lo1[i].x, lo1[i].y, lo1[i].z, lo1[i].w};
      #pragma unroll
      for (int j = 0; j < 8; ++j) {
        unsigned v = (unsigned)f2bf(fe[j]) | ((unsigned)f2bf(fo[j]) << 16);
        *(unsigned*)&stag[(8*wo + j)*136 + 2*c2] = v;
      }
    }
  }
  __syncthreads();

  // ---------------- issue global loads for R (fly under GEMM-L) ----------------
  float4 re0[8], re1[8], ro0[8], ro1[8];
  #pragma unroll
  for (int i = 0; i < 8; ++i) {
    int tau = tid + 256*i;
    if (tau < 1920) {
      int c2 = tau & 63, wo = tau >> 6;
      size_t off = base + (size_t)(2*c2)*PLANE + 8*wo;
      re0[i] = *(const float4*)(xR + off);
      re1[i] = *(const float4*)(xR + off + 4);
      ro0[i] = *(const float4*)(xR + off + PLANE);
      ro1[i] = *(const float4*)(xR + off + PLANE + 4);
    }
  }

  // ---------------- GEMM + normalize + swizzled store ----------------
  const int mrow = lane & 15;
  const int kg   = lane >> 4;
  const int nt0  = wv*4;

  auto gemm_norm = [&](unsigned short* dst) {
    f32x4 acc[4][4];
    #pragma unroll
    for (int i = 0; i < 4; ++i)
      #pragma unroll
      for (int mt = 0; mt < 4; ++mt)
        acc[i][mt] = (f32x4){0.f,0.f,0.f,0.f};

    #pragma unroll
    for (int ks = 0; ks < 4; ++ks) {
      short8 af[4];
      #pragma unroll
      for (int mt = 0; mt < 4; ++mt)
        af[mt] = *(const short8*)&phis[(16*mt + mrow)*136 + 32*ks + 8*kg];
      #pragma unroll
      for (int i = 0; i < 4; ++i) {
        int nt = nt0 + i;
        if (nt < 15) {
          short8 bfv = *(const short8*)&stag[(16*nt + mrow)*136 + 32*ks + 8*kg];
          #pragma unroll
          for (int mt = 0; mt < 4; ++mt)
            acc[i][mt] = __builtin_amdgcn_mfma_f32_16x16x32_bf16(af[mt], bfv, acc[i][mt], 0, 0, 0);
        }
      }
    }
    #pragma unroll
    for (int i = 0; i < 4; ++i) {
      int nt = nt0 + i;
      if (nt >= 15) continue;
      float ss = 0.f;
      #pragma unroll
      for (int mt = 0; mt < 4; ++mt)
        #pragma unroll
        for (int r = 0; r < 4; ++r)
          ss += acc[i][mt][r]*acc[i][mt][r];
      ss += __shfl_xor(ss, 16, 64);
      ss += __shfl_xor(ss, 32, 64);
      float inv = 1.f/(sqrtf(ss) + 1e-6f);
      int n = 16*nt + mrow;
      #pragma unroll
      for (int mt = 0; mt < 4; ++mt) {
        int e0 = 16*mt + 4*kg;
        ushort4 pk;
        pk.x = f2bf(acc[i][mt][0]*inv);
        pk.y = f2bf(acc[i][mt][1]*inv);
        pk.z = f2bf(acc[i][mt][2]*inv);
        pk.w = f2bf(acc[i][mt][3]*inv);
        int pos = n*64 + (((e0>>3) ^ (n&7))<<3) + (e0&7);
        *(ushort4*)&dst[pos] = pk;
      }
    }
  };

  gemm_norm(FLb);
  __syncthreads();                 // all waves done reading stag + FLb written

  // ---------------- R transposed write (fp32->bf16) + GEMM ----------------
  #pragma unroll
  for (int i = 0; i < 8; ++i) {
    int tau = tid + 256*i;
    if (tau < 1920) {
      int c2 = tau & 63, wo = tau >> 6;
      float fe[8] = {re0[i].x, re0[i].y, re0[i].z, re0[i].w,
                     re1[i].x, re1[i].y, re1[i].z, re1[i].w};
      float fo[8] = {ro0[i].x, ro0[i].y, ro0[i].z, ro0[i].w,
                     ro1[i].x, ro1[i].y, ro1[i].z, ro1[i].w};
      #pragma unroll
      for (int j = 0; j < 8; ++j) {
        unsigned v = (unsigned)f2bf(fe[j]) | ((unsigned)f2bf(fo[j]) << 16);
        *(unsigned*)&stag[(8*wo + j)*136 + 2*c2] = v;
      }
    }
  }
  __syncthreads();

  gemm_norm(FRb);
  __syncthreads();                 // FRb ready

  // ---------------- cost phase: 10 dots + blend, fp32 I/O ----------------
  if (tid < NW) {
    const int p = tid;
    float d0v = d0g[(b*NH + h)*NW + p];
    float xf  = (float)p - d0v;
    float x0  = floorf(xf);
    float wfr = xf - x0;
    int jb = (int)x0 - 4;

    float fl[64];
    #pragma unroll
    for (int c = 0; c < 8; ++c) {
      uint4 raw = *(const uint4*)&FLb[p*64 + ((c ^ (p&7))<<3)];
      fl[8*c+0]=bfl(raw.x); fl[8*c+1]=bfh(raw.x);
      fl[8*c+2]=bfl(raw.y); fl[8*c+3]=bfh(raw.y);
      fl[8*c+4]=bfl(raw.z); fl[8*c+5]=bfh(raw.z);
      fl[8*c+6]=bfl(raw.w); fl[8*c+7]=bfh(raw.w);
    }

    float D[10];
    #pragma unroll
    for (int t = 0; t < 10; ++t) {
      int j = jb + t;
      j = j < 0 ? 0 : (j > NW-1 ? NW-1 : j);
      float s = 0.f;
      #pragma unroll
      for (int c = 0; c < 8; ++c) {
        uint4 raw = *(const uint4*)&FRb[j*64 + ((c ^ (j&7))<<3)];
        s += fl[8*c+0]*bfl(raw.x) + fl[8*c+1]*bfh(raw.x)
           + fl[8*c+2]*bfl(raw.y) + fl[8*c+3]*bfh(raw.y)
           + fl[8*c+4]*bfl(raw.z) + fl[8*c+5]*bfh(raw.z)
           + fl[8*c+6]*bfl(raw.w) + fl[8*c+7]*bfh(raw.w);
      }
      D[t] = s;
    }

    size_t ob = (size_t)(b*NK)*PLANE + (size_t)h*NW + p;
    #pragma unroll
    for (int k = 0; k < NK; ++k) {
      int t0 = 8 - k;                       // delta_k = k-4; floor index = x0 - delta_k
      float cv = (1.f - wfr)*D[t0] + wfr*D[t0+1];
      outg[ob + (size_t)k*PLANE] = cv;
    }
  }
}

extern "C" void kernel_launch(void* const* d_in, const int* in_sizes, int n_in,
                              void* d_out, int out_size, void* d_ws, size_t ws_size,
                              hipStream_t stream) {
  const float* xL   = (const float*)d_in[0];
  const float* xR   = (const float*)d_in[1];
  const float* d0g  = (const float*)d_in[2];
  const float* phig = (const float*)d_in[3];
  float* outg = (float*)d_out;
  corr_kernel<<<dim3(NB*NH), dim3(256), 0, stream>>>(xL, xR, d0g, phig, outg);
}

// Round 3
// 160.369 us; speedup vs baseline: 1.0874x; 1.0874x over previous
//
#include <hip/hip_runtime.h>

#define NB 4
#define NC 128
#define NH 128
#define NW 240
#define NE 64
#define NK 9
#define PLANE (NH*NW)        // 30720: stride between channels
#define CHW (NC*PLANE)
#define XS 244               // xs row stride in ushort (488 B: 8B-aligned, de-conflicted)

typedef __attribute__((ext_vector_type(8))) short short8;
typedef __attribute__((ext_vector_type(4))) float f32x4;

__device__ __forceinline__ unsigned short f2bf(float f){
  unsigned u = __float_as_uint(f);
  u += 0x7fffu + ((u>>16)&1u);           // RNE
  return (unsigned short)(u>>16);
}
__device__ __forceinline__ float bfl(unsigned v){ return __uint_as_float(v<<16); }
__device__ __forceinline__ float bfh(unsigned v){ return __uint_as_float(v & 0xffff0000u); }

// LDS: xs 128x244 bf16 ([c][w] natural layout), phis 64x136 bf16,
// FLb/FRb 240x64 bf16 XOR-swizzled. Total 141,312 B -> 1 block/CU.
__global__ __launch_bounds__(256, 1)
void corr_kernel(const float* __restrict__ xL,
                 const float* __restrict__ xR,
                 const float* __restrict__ d0g,
                 const float* __restrict__ phig,
                 float* __restrict__ outg)
{
  __shared__ __attribute__((aligned(16))) unsigned short xs[NC*XS];
  __shared__ __attribute__((aligned(16))) unsigned short phis[NE*136];
  __shared__ __attribute__((aligned(16))) unsigned short FLb[NW*64];
  __shared__ __attribute__((aligned(16))) unsigned short FRb[NW*64];

  const int tid  = threadIdx.x;
  const int lane = tid & 63;
  const int wv   = tid >> 6;
  const int b    = blockIdx.x >> 7;
  const int h    = blockIdx.x & 127;
  const size_t base = (size_t)b*CHW + (size_t)h*NW;

  // d0 for the cost phase — load early, keep in register
  float d0v = 0.f;
  if (tid < NW) d0v = d0g[(b*NH + h)*NW + tid];

  // ---------------- stage phi (coalesced fp32 -> bf16) ----------------
  #pragma unroll
  for (int i = 0; i < 8; ++i) {
    int idx = i*256 + tid;               // 0..2047 float4 of phi
    int e = idx >> 5, q = idx & 31;
    float4 v = *(const float4*)(phig + e*128 + 4*q);
    uint2 pk;
    pk.x = (unsigned)f2bf(v.x) | ((unsigned)f2bf(v.y) << 16);
    pk.y = (unsigned)f2bf(v.z) | ((unsigned)f2bf(v.w) << 16);
    *(uint2*)&phis[e*136 + 4*q] = pk;
  }

  // ---------------- stage L: coalesced along W ----------------
  // 7680 float4 per tensor: idx = c*60 + s, lanes consecutive in s.
  #pragma unroll
  for (int i = 0; i < 30; ++i) {
    int idx = i*256 + tid;
    int c = idx / 60, s = idx - 60*c;
    float4 v = *(const float4*)(xL + base + (size_t)c*PLANE + 4*s);
    uint2 pk;
    pk.x = (unsigned)f2bf(v.x) | ((unsigned)f2bf(v.y) << 16);
    pk.y = (unsigned)f2bf(v.z) | ((unsigned)f2bf(v.w) << 16);
    *(uint2*)&xs[c*XS + 4*s] = pk;
  }
  __syncthreads();

  // ---------------- GEMM + normalize + swizzled store ----------------
  const int mrow = lane & 15;
  const int kg   = lane >> 4;
  const int nt0  = wv*4;

  auto gemm_norm = [&](unsigned short* dst) {
    f32x4 acc[4][4];
    #pragma unroll
    for (int i = 0; i < 4; ++i)
      #pragma unroll
      for (int mt = 0; mt < 4; ++mt)
        acc[i][mt] = (f32x4){0.f,0.f,0.f,0.f};

    #pragma unroll
    for (int ks = 0; ks < 4; ++ks) {
      short8 af[4];
      #pragma unroll
      for (int mt = 0; mt < 4; ++mt)
        af[mt] = *(const short8*)&phis[(16*mt + mrow)*136 + 32*ks + 8*kg];
      const int r0 = 32*ks + 8*kg;       // channel base for this lane's k-group
      #pragma unroll
      for (int i = 0; i < 4; ++i) {
        int nt = nt0 + i;
        if (nt < 15) {
          int col = 16*nt + mrow;        // w
          short8 bfv;
          #pragma unroll
          for (int j = 0; j < 8; ++j)
            bfv[j] = (short)xs[(r0 + j)*XS + col];
          #pragma unroll
          for (int mt = 0; mt < 4; ++mt)
            acc[i][mt] = __builtin_amdgcn_mfma_f32_16x16x32_bf16(af[mt], bfv, acc[i][mt], 0, 0, 0);
        }
      }
    }
    #pragma unroll
    for (int i = 0; i < 4; ++i) {
      int nt = nt0 + i;
      if (nt >= 15) continue;
      float ss = 0.f;
      #pragma unroll
      for (int mt = 0; mt < 4; ++mt)
        #pragma unroll
        for (int r = 0; r < 4; ++r)
          ss += acc[i][mt][r]*acc[i][mt][r];
      ss += __shfl_xor(ss, 16, 64);
      ss += __shfl_xor(ss, 32, 64);
      float inv = 1.f/(sqrtf(ss) + 1e-6f);
      int n = 16*nt + mrow;
      #pragma unroll
      for (int mt = 0; mt < 4; ++mt) {
        int e0 = 16*mt + 4*kg;
        ushort4 pk;
        pk.x = f2bf(acc[i][mt][0]*inv);
        pk.y = f2bf(acc[i][mt][1]*inv);
        pk.z = f2bf(acc[i][mt][2]*inv);
        pk.w = f2bf(acc[i][mt][3]*inv);
        int pos = n*64 + (((e0>>3) ^ (n&7))<<3) + (e0&7);
        *(ushort4*)&dst[pos] = pk;
      }
    }
  };

  gemm_norm(FLb);
  __syncthreads();                 // all waves done reading xs + FLb written

  // ---------------- stage R (coalesced) ----------------
  #pragma unroll
  for (int i = 0; i < 30; ++i) {
    int idx = i*256 + tid;
    int c = idx / 60, s = idx - 60*c;
    float4 v = *(const float4*)(xR + base + (size_t)c*PLANE + 4*s);
    uint2 pk;
    pk.x = (unsigned)f2bf(v.x) | ((unsigned)f2bf(v.y) << 16);
    pk.y = (unsigned)f2bf(v.z) | ((unsigned)f2bf(v.w) << 16);
    *(uint2*)&xs[c*XS + 4*s] = pk;
  }
  __syncthreads();

  gemm_norm(FRb);
  __syncthreads();                 // FRb ready

  // ---------------- cost phase: 10 dots + blend, fp32 I/O ----------------
  if (tid < NW) {
    const int p = tid;
    float xf  = (float)p - d0v;
    float x0  = floorf(xf);
    float wfr = xf - x0;
    int jb = (int)x0 - 4;

    float fl[64];
    #pragma unroll
    for (int c = 0; c < 8; ++c) {
      uint4 raw = *(const uint4*)&FLb[p*64 + ((c ^ (p&7))<<3)];
      fl[8*c+0]=bfl(raw.x); fl[8*c+1]=bfh(raw.x);
      fl[8*c+2]=bfl(raw.y); fl[8*c+3]=bfh(raw.y);
      fl[8*c+4]=bfl(raw.z); fl[8*c+5]=bfh(raw.z);
      fl[8*c+6]=bfl(raw.w); fl[8*c+7]=bfh(raw.w);
    }

    float D[10];
    #pragma unroll
    for (int t = 0; t < 10; ++t) {
      int j = jb + t;
      j = j < 0 ? 0 : (j > NW-1 ? NW-1 : j);
      float s = 0.f;
      #pragma unroll
      for (int c = 0; c < 8; ++c) {
        uint4 raw = *(const uint4*)&FRb[j*64 + ((c ^ (j&7))<<3)];
        s += fl[8*c+0]*bfl(raw.x) + fl[8*c+1]*bfh(raw.x)
           + fl[8*c+2]*bfl(raw.y) + fl[8*c+3]*bfh(raw.y)
           + fl[8*c+4]*bfl(raw.z) + fl[8*c+5]*bfh(raw.z)
           + fl[8*c+6]*bfl(raw.w) + fl[8*c+7]*bfh(raw.w);
      }
      D[t] = s;
    }

    size_t ob = (size_t)(b*NK)*PLANE + (size_t)h*NW + p;
    #pragma unroll
    for (int k = 0; k < NK; ++k) {
      int t0 = 8 - k;                       // delta_k = k-4; floor index = x0 - delta_k
      float cv = (1.f - wfr)*D[t0] + wfr*D[t0+1];
      outg[ob + (size_t)k*PLANE] = cv;
    }
  }
}

extern "C" void kernel_launch(void* const* d_in, const int* in_sizes, int n_in,
                              void* d_out, int out_size, void* d_ws, size_t ws_size,
                              hipStream_t stream) {
  const float* xL   = (const float*)d_in[0];
  const float* xR   = (const float*)d_in[1];
  const float* d0g  = (const float*)d_in[2];
  const float* phig = (const float*)d_in[3];
  float* outg = (float*)d_out;
  corr_kernel<<<dim3(NB*NH), dim3(256), 0, stream>>>(xL, xR, d0g, phig, outg);
}

// Round 4
// 157.962 us; speedup vs baseline: 1.1039x; 1.0152x over previous
//
#include <hip/hip_runtime.h>
#include <hip/hip_bf16.h>

#define NB 4
#define NC 128
#define NH 128
#define NW 240
#define NE 64
#define NK 9
#define PLANE (NH*NW)        // 30720: stride between channels
#define CHW (NC*PLANE)
#define XS 244               // xs row stride in ushort (488 B: 8B-aligned, de-conflicted)

typedef __attribute__((ext_vector_type(8))) short short8;
typedef __attribute__((ext_vector_type(4))) float f32x4;

__device__ __forceinline__ unsigned pk2bf(float x, float y){
  __hip_bfloat162 h = __float22bfloat162_rn(make_float2(x, y));  // v_cvt_pk_bf16_f32 on gfx950
  return *(unsigned*)&h;
}
__device__ __forceinline__ unsigned short f2bf(float f){
  unsigned u = __float_as_uint(f);
  u += 0x7fffu + ((u>>16)&1u);           // RNE
  return (unsigned short)(u>>16);
}
__device__ __forceinline__ float bfl(unsigned v){ return __uint_as_float(v<<16); }
__device__ __forceinline__ float bfh(unsigned v){ return __uint_as_float(v & 0xffff0000u); }

// LDS: xs 128x244 bf16 ([c][w]), phis 64x136 bf16, FLb/FRb 240x64 bf16 swizzled.
// 141,312 B -> 1 block/CU, but 1024 threads -> 16 waves -> 4 waves/SIMD.
__global__ __launch_bounds__(1024, 4)
void corr_kernel(const float* __restrict__ xL,
                 const float* __restrict__ xR,
                 const float* __restrict__ d0g,
                 const float* __restrict__ phig,
                 float* __restrict__ outg)
{
  __shared__ __attribute__((aligned(16))) unsigned short xs[NC*XS];
  __shared__ __attribute__((aligned(16))) unsigned short phis[NE*136];
  __shared__ __attribute__((aligned(16))) unsigned short FLb[NW*64];
  __shared__ __attribute__((aligned(16))) unsigned short FRb[NW*64];

  const int tid  = threadIdx.x;
  const int lane = tid & 63;
  const int wv   = tid >> 6;
  const int b    = blockIdx.x >> 7;
  const int h    = blockIdx.x & 127;
  const size_t base = (size_t)b*CHW + (size_t)h*NW;

  // d0 for the cost phase — load early, keep in register
  float d0v = 0.f;
  if (tid < NW) d0v = d0g[(b*NH + h)*NW + tid];

  // ---------------- stage phi (coalesced fp32 -> bf16): 2048 float4 ----------------
  #pragma unroll
  for (int i = 0; i < 2; ++i) {
    int idx = i*1024 + tid;
    int e = idx >> 5, q = idx & 31;
    float4 v = *(const float4*)(phig + e*128 + 4*q);
    uint2 pk; pk.x = pk2bf(v.x, v.y); pk.y = pk2bf(v.z, v.w);
    *(uint2*)&phis[e*136 + 4*q] = pk;
  }

  // ---------------- stage L: coalesced along W (60 float4 per channel) ----------------
  #pragma unroll
  for (int i = 0; i < 8; ++i) {
    int tau = i*1024 + tid;
    int c = tau >> 6, s = tau & 63;
    if (s < 60) {
      float4 v = *(const float4*)(xL + base + (size_t)c*PLANE + 4*s);
      uint2 pk; pk.x = pk2bf(v.x, v.y); pk.y = pk2bf(v.z, v.w);
      *(uint2*)&xs[c*XS + 4*s] = pk;
    }
  }
  __syncthreads();

  // ---------------- GEMM + normalize + swizzled store ----------------
  const int mrow = lane & 15;
  const int kg   = lane >> 4;
  const int nt   = wv;             // one N-tile per wave, nt<15 active

  auto gemm_norm = [&](unsigned short* dst) {
    f32x4 acc[4];
    #pragma unroll
    for (int mt = 0; mt < 4; ++mt) acc[mt] = (f32x4){0.f,0.f,0.f,0.f};

    if (nt < 15) {
      const int col = 16*nt + mrow;
      #pragma unroll
      for (int ks = 0; ks < 4; ++ks) {
        const int r0 = 32*ks + 8*kg;
        short8 bfv;
        #pragma unroll
        for (int j = 0; j < 8; ++j)
          bfv[j] = (short)xs[(r0 + j)*XS + col];
        #pragma unroll
        for (int mt = 0; mt < 4; ++mt) {
          short8 af = *(const short8*)&phis[(16*mt + mrow)*136 + 32*ks + 8*kg];
          acc[mt] = __builtin_amdgcn_mfma_f32_16x16x32_bf16(af, bfv, acc[mt], 0, 0, 0);
        }
      }
      float ss = 0.f;
      #pragma unroll
      for (int mt = 0; mt < 4; ++mt)
        #pragma unroll
        for (int r = 0; r < 4; ++r)
          ss += acc[mt][r]*acc[mt][r];
      ss += __shfl_xor(ss, 16, 64);
      ss += __shfl_xor(ss, 32, 64);
      float inv = 1.f/(sqrtf(ss) + 1e-6f);
      int n = 16*nt + mrow;
      #pragma unroll
      for (int mt = 0; mt < 4; ++mt) {
        int e0 = 16*mt + 4*kg;
        ushort4 pk;
        pk.x = f2bf(acc[mt][0]*inv);
        pk.y = f2bf(acc[mt][1]*inv);
        pk.z = f2bf(acc[mt][2]*inv);
        pk.w = f2bf(acc[mt][3]*inv);
        int pos = n*64 + (((e0>>3) ^ (n&7))<<3) + (e0&7);
        *(ushort4*)&dst[pos] = pk;
      }
    }
  };

  gemm_norm(FLb);
  __syncthreads();                 // all waves done reading xs + FLb written

  // ---------------- stage R (coalesced) ----------------
  #pragma unroll
  for (int i = 0; i < 8; ++i) {
    int tau = i*1024 + tid;
    int c = tau >> 6, s = tau & 63;
    if (s < 60) {
      float4 v = *(const float4*)(xR + base + (size_t)c*PLANE + 4*s);
      uint2 pk; pk.x = pk2bf(v.x, v.y); pk.y = pk2bf(v.z, v.w);
      *(uint2*)&xs[c*XS + 4*s] = pk;
    }
  }
  __syncthreads();

  gemm_norm(FRb);
  __syncthreads();                 // FRb ready

  // ---------------- cost phase: 10 dots + blend, fp32 I/O ----------------
  if (tid < NW) {
    const int p = tid;
    float xf  = (float)p - d0v;
    float x0  = floorf(xf);
    float wfr = xf - x0;
    int jb = (int)x0 - 4;

    float fl[64];
    #pragma unroll
    for (int c = 0; c < 8; ++c) {
      uint4 raw = *(const uint4*)&FLb[p*64 + ((c ^ (p&7))<<3)];
      fl[8*c+0]=bfl(raw.x); fl[8*c+1]=bfh(raw.x);
      fl[8*c+2]=bfl(raw.y); fl[8*c+3]=bfh(raw.y);
      fl[8*c+4]=bfl(raw.z); fl[8*c+5]=bfh(raw.z);
      fl[8*c+6]=bfl(raw.w); fl[8*c+7]=bfh(raw.w);
    }

    float D[10];
    #pragma unroll
    for (int t = 0; t < 10; ++t) {
      int j = jb + t;
      j = j < 0 ? 0 : (j > NW-1 ? NW-1 : j);
      float s = 0.f;
      #pragma unroll
      for (int c = 0; c < 8; ++c) {
        uint4 raw = *(const uint4*)&FRb[j*64 + ((c ^ (j&7))<<3)];
        s += fl[8*c+0]*bfl(raw.x) + fl[8*c+1]*bfh(raw.x)
           + fl[8*c+2]*bfl(raw.y) + fl[8*c+3]*bfh(raw.y)
           + fl[8*c+4]*bfl(raw.z) + fl[8*c+5]*bfh(raw.z)
           + fl[8*c+6]*bfl(raw.w) + fl[8*c+7]*bfh(raw.w);
      }
      D[t] = s;
    }

    size_t ob = (size_t)(b*NK)*PLANE + (size_t)h*NW + p;
    #pragma unroll
    for (int k = 0; k < NK; ++k) {
      int t0 = 8 - k;                       // delta_k = k-4; floor index = x0 - delta_k
      float cv = (1.f - wfr)*D[t0] + wfr*D[t0+1];
      outg[ob + (size_t)k*PLANE] = cv;
    }
  }
}

extern "C" void kernel_launch(void* const* d_in, const int* in_sizes, int n_in,
                              void* d_out, int out_size, void* d_ws, size_t ws_size,
                              hipStream_t stream) {
  const float* xL   = (const float*)d_in[0];
  const float* xR   = (const float*)d_in[1];
  const float* d0g  = (const float*)d_in[2];
  const float* phig = (const float*)d_in[3];
  float* outg = (float*)d_out;
  corr_kernel<<<dim3(NB*NH), dim3(1024), 0, stream>>>(xL, xR, d0g, phig, outg);
}